// Round 10
// baseline (379.474 us; speedup 1.0000x reference)
//
#include <hip/hip_runtime.h>

typedef __attribute__((ext_vector_type(8))) short s8v;
typedef __attribute__((ext_vector_type(4))) short s4v;
typedef __attribute__((ext_vector_type(4))) float f4v;

constexpr int SEQ = 2048;
constexpr int EMB = 512;
constexpr int BATCH = 8;
constexpr int BS = BATCH * SEQ;  // 16384
constexpr int NCH = 32;          // scan chunks per batch (64 rows each)
constexpr int NBLK = 512;        // mega-kernel grid (2 blocks/CU x 256 CUs)

#define DEVINL __device__ __forceinline__

DEVINL float bf2f(short s) {
    union { unsigned u; float f; } v;
    v.u = ((unsigned)(unsigned short)s) << 16;
    return v.f;
}
DEVINL short f2bf(float f) {
    union { float f; unsigned u; } v; v.f = f;
    unsigned u = v.u;
    return (short)((u + 0x7FFFu + ((u >> 16) & 1u)) >> 16);
}
DEVINL f4v mfma16(s8v a, s8v b, f4v c) {
    return __builtin_amdgcn_mfma_f32_16x16x32_bf16(a, b, c, 0, 0, 0);
}
DEVINL s8v pack8(float4 a, float4 b) {
    s8v o;
    o[0] = f2bf(a.x); o[1] = f2bf(a.y); o[2] = f2bf(a.z); o[3] = f2bf(a.w);
    o[4] = f2bf(b.x); o[5] = f2bf(b.y); o[6] = f2bf(b.z); o[7] = f2bf(b.w);
    return o;
}
DEVINL void gload16(const short* g, short* l) {
    __builtin_amdgcn_global_load_lds(
        (const __attribute__((address_space(1))) void*)g,
        (__attribute__((address_space(3))) void*)l, 16, 0, 0);
}

// ---- software grid barrier (agent scope: correct across XCD L2s) ----
DEVINL void gridbar(unsigned* cnt, unsigned* gen) {
    __syncthreads();
    if (threadIdx.x == 0) {
        unsigned g = __hip_atomic_load(gen, __ATOMIC_RELAXED,
                                       __HIP_MEMORY_SCOPE_AGENT);
        unsigned a = __hip_atomic_fetch_add(cnt, 1u, __ATOMIC_ACQ_REL,
                                            __HIP_MEMORY_SCOPE_AGENT);
        if (a == (unsigned)(NBLK - 1)) {
            __hip_atomic_store(cnt, 0u, __ATOMIC_RELAXED,
                               __HIP_MEMORY_SCOPE_AGENT);
            __hip_atomic_store(gen, g + 1u, __ATOMIC_RELEASE,
                               __HIP_MEMORY_SCOPE_AGENT);
        } else {
            while (__hip_atomic_load(gen, __ATOMIC_ACQUIRE,
                                     __HIP_MEMORY_SCOPE_AGENT) == g)
                __builtin_amdgcn_s_sleep(2);
        }
    }
    __syncthreads();
}

// ---------------- phase bodies (verbatim from the R8 kernels) ----------------

// prep item: [0,128) v_W cast; [128,320) 64x64 transpose; [320,576) scan_p1;
// [576,592) bc matvec
DEVINL void prep_item(int item, int tid, char* Ub,
                      const float* v_W, const float* out_W, const float* w1,
                      const float* w2, const float* K, const float* v_b,
                      const float* out_b, short* VWb, short* WoT, short* W1T,
                      short* W2T, float* partial, float* bc) {
    if (item < 128) {
        int i = item * 256 + tid;
        const float* p = v_W + (size_t)i * 8;
        float4 a = *(const float4*)p;
        float4 b = *(const float4*)(p + 4);
        *(s8v*)(VWb + (size_t)i * 8) = pack8(a, b);
    } else if (item < 320) {
        short(*tile)[72] = (short(*)[72])Ub;  // 9KB
        int t = item - 128;
        int sel = t >> 6;
        const float* W = (sel == 0) ? out_W : (sel == 1 ? w1 : w2);
        short* WT = (sel == 0) ? WoT : (sel == 1 ? W1T : W2T);
        int tileid = t & 63;
        int kt = (tileid >> 3) * 64, nt = (tileid & 7) * 64;
        int r = tid >> 4;
        int c4 = (tid & 15) * 4;
#pragma unroll
        for (int p = 0; p < 4; p++) {
            int row = p * 16 + r;
            float4 v = *(const float4*)(W + (size_t)(kt + row) * EMB + nt + c4);
            tile[row][c4 + 0] = f2bf(v.x);
            tile[row][c4 + 1] = f2bf(v.y);
            tile[row][c4 + 2] = f2bf(v.z);
            tile[row][c4 + 3] = f2bf(v.w);
        }
        __syncthreads();
        int kl = (tid & 7) * 8;
        int nl = tid >> 3;
#pragma unroll
        for (int h = 0; h < 2; h++) {
            int n = h * 32 + nl;
            s8v o;
#pragma unroll
            for (int e = 0; e < 8; e++) o[e] = tile[kl + e][n];
            *(s8v*)(WT + (size_t)(nt + n) * EMB + kt + kl) = o;
        }
    } else if (item < 576) {
        float* sh = (float*)Ub;  // 8KB
        int bb = item - 320;
        int b = bb >> 5, c = bb & (NCH - 1);
        int g = tid >> 6, lane = tid & 63;
        int col8 = lane * 8;
        const float* base = K + ((size_t)b * SEQ + c * 64 + g * 16) * EMB + col8;
        float acc[8] = {};
        for (int it = 0; it < 16; it++) {
            float4 a = *(const float4*)(base + (size_t)it * EMB);
            float4 b2 = *(const float4*)(base + (size_t)it * EMB + 4);
            acc[0] += a.x; acc[1] += a.y; acc[2] += a.z; acc[3] += a.w;
            acc[4] += b2.x; acc[5] += b2.y; acc[6] += b2.z; acc[7] += b2.w;
        }
#pragma unroll
        for (int j = 0; j < 8; j++) sh[g * EMB + col8 + j] = acc[j];
        __syncthreads();
        if (g == 0) {
#pragma unroll
            for (int j = 0; j < 8; j++) {
                int e = col8 + j;
                partial[((size_t)b * NCH + c) * EMB + e] =
                    sh[e] + sh[EMB + e] + sh[2 * EMB + e] + sh[3 * EMB + e];
            }
        }
    } else {
        float* sh = (float*)Ub;  // 1KB
        int bb = item - 576;
        int nl = tid & 31, ms = tid >> 5;
        int n = bb * 32 + nl;
        float acc = 0.f;
#pragma unroll 8
        for (int mm = 0; mm < 64; mm++) {
            int m = ms * 64 + mm;
            acc = fmaf(v_b[m], out_W[(size_t)m * EMB + n], acc);
        }
        sh[tid] = acc;
        __syncthreads();
        if (tid < 32) {
            float s = 0.f;
#pragma unroll
            for (int j = 0; j < 8; j++) s += sh[j * 32 + tid];
            bc[bb * 32 + tid] = s + out_b[bb * 32 + tid];
        }
    }
}

// scan phase 2: SK[i][e] = (sum_{j>i} k[j][e]) / (SEQ-1-i)
DEVINL void scan2_item(int bid, int tid, char* Ub, const float* K,
                       const float* partial, short* SK) {
    float* wsum = (float*)Ub;  // [4][512] = 8KB
    int b = bid >> 5, c = bid & (NCH - 1);
    int g = tid >> 6, lane = tid & 63;
    int col8 = lane * 8;

    float off[8] = {}, alltot[8] = {};
    for (int cc = 0; cc < NCH; cc++) {
        const float* pp = partial + ((size_t)b * NCH + cc) * EMB + col8;
        float4 pa = *(const float4*)pp;
        float4 pb = *(const float4*)(pp + 4);
        float v[8] = {pa.x, pa.y, pa.z, pa.w, pb.x, pb.y, pb.z, pb.w};
#pragma unroll
        for (int j = 0; j < 8; j++) {
            alltot[j] += v[j];
            if (cc > c) off[j] += v[j];
        }
    }
    const float* base = K + ((size_t)b * SEQ + c * 64 + g * 16) * EMB + col8;
    {
        float acc[8] = {};
        for (int it = 0; it < 16; it++) {
            float4 a = *(const float4*)(base + (size_t)it * EMB);
            float4 bb = *(const float4*)(base + (size_t)it * EMB + 4);
            acc[0] += a.x; acc[1] += a.y; acc[2] += a.z; acc[3] += a.w;
            acc[4] += bb.x; acc[5] += bb.y; acc[6] += bb.z; acc[7] += bb.w;
        }
#pragma unroll
        for (int j = 0; j < 8; j++) wsum[g * EMB + col8 + j] = acc[j];
    }
    __syncthreads();
    float suf[8];
#pragma unroll
    for (int j = 0; j < 8; j++) {
        float s = off[j];
        for (int gg = g + 1; gg < 4; gg++) s += wsum[gg * EMB + col8 + j];
        suf[j] = s;
    }
    short* skbase = SK + ((size_t)b * SEQ + c * 64 + g * 16) * EMB + col8;
    for (int it = 15; it >= 0; it--) {
        int gi = c * 64 + g * 16 + it;
        float4 a = *(const float4*)(base + (size_t)it * EMB);
        float4 bb = *(const float4*)(base + (size_t)it * EMB + 4);
        s8v o;
        if (gi == SEQ - 1) {
            float inv = 1.0f / (float)SEQ;
#pragma unroll
            for (int j = 0; j < 8; j++) o[j] = f2bf(alltot[j] * inv);
        } else {
            float inv = __builtin_amdgcn_rcpf((float)(SEQ - 1 - gi));
#pragma unroll
            for (int j = 0; j < 8; j++) o[j] = f2bf(suf[j] * inv);
        }
        *(s8v*)(skbase + (size_t)it * EMB) = o;
        suf[0] += a.x; suf[1] += a.y; suf[2] += a.z; suf[3] += a.w;
        suf[4] += bb.x; suf[5] += bb.y; suf[6] += bb.z; suf[7] += bb.w;
    }
}

// m97-style 128x128 GEMM tile. EPI 0: +bias->bf16; 1: +bias,relu->bf16;
// 2: no bias, store transposed (C[col][row], stride EMB)
template <int EPI>
DEVINL void gemm_tile(char* Ub, int wg, int tid, const short* A,
                      const short* B, const float* bias, short* C) {
    short* L = (short*)Ub;  // 2 x 16384 shorts = 64KB
    const int mt = wg >> 2, nt = wg & 3;
    const int mbase = mt * 128, nbase = nt * 128;
    const int w = tid >> 6, lane = tid & 63;
    const int lr = lane & 15, kg = lane >> 4;
    const int wr = w >> 1, wc = w & 1;

    const short* gA[4];
    const short* gB[4];
    short* lA[4];
    short* lB[4];
#pragma unroll
    for (int inst = 0; inst < 4; inst++) {
        int Ui = inst * 256 + w * 64 + lane;  // 16B unit index, 0..1023
        int row = Ui >> 3, cu = Ui & 7;
        int csrc = cu ^ (row & 7);
        gA[inst] = A + (size_t)(mbase + row) * EMB + csrc * 8;
        gB[inst] = B + (size_t)(nbase + row) * EMB + csrc * 8;
        lA[inst] = L + (inst * 256 + w * 64) * 8;
        lB[inst] = L + 8192 + (inst * 256 + w * 64) * 8;
    }

    int aoff[4][2], boff[4][2];
#pragma unroll
    for (int m = 0; m < 4; m++)
#pragma unroll
        for (int ks = 0; ks < 2; ks++) {
            int row = wr * 64 + m * 16 + lr;
            int cu = (ks * 4 + kg) ^ (row & 7);
            aoff[m][ks] = row * 64 + cu * 8;
        }
#pragma unroll
    for (int n = 0; n < 4; n++)
#pragma unroll
        for (int ks = 0; ks < 2; ks++) {
            int row = wc * 64 + n * 16 + lr;
            int cu = (ks * 4 + kg) ^ (row & 7);
            boff[n][ks] = 8192 + row * 64 + cu * 8;
        }

    auto stage = [&](int kt, int d) {
        int koff = kt * 64;  // shorts
        int dd = d * 16384;
#pragma unroll
        for (int inst = 0; inst < 4; inst++)
            gload16(gA[inst] + koff, lA[inst] + dd);
#pragma unroll
        for (int inst = 0; inst < 4; inst++)
            gload16(gB[inst] + koff, lB[inst] + dd);
    };

    f4v acc[4][4] = {};
    stage(0, 0);
    int cur = 0;
    for (int kt = 0; kt < 8; kt++) {
        __syncthreads();  // drains vmcnt: buf[cur] staged & visible
        if (kt < 7) stage(kt + 1, cur ^ 1);
        const short* base = L + cur * 16384;
        s8v afr[4][2], bfr[4][2];
#pragma unroll
        for (int m = 0; m < 4; m++)
#pragma unroll
            for (int ks = 0; ks < 2; ks++)
                afr[m][ks] = *(const s8v*)(base + aoff[m][ks]);
#pragma unroll
        for (int n = 0; n < 4; n++)
#pragma unroll
            for (int ks = 0; ks < 2; ks++)
                bfr[n][ks] = *(const s8v*)(base + boff[n][ks]);
#pragma unroll
        for (int ks = 0; ks < 2; ks++)
#pragma unroll
            for (int m = 0; m < 4; m++)
#pragma unroll
                for (int n = 0; n < 4; n++)
                    acc[m][n] = mfma16(afr[m][ks], bfr[n][ks], acc[m][n]);
        cur ^= 1;
    }
    __syncthreads();  // protect LDS for any following phase

    if constexpr (EPI == 2) {
#pragma unroll
        for (int m = 0; m < 4; m++)
#pragma unroll
            for (int n = 0; n < 4; n++) {
                int col = nbase + wc * 64 + n * 16 + lr;
                int row0 = mbase + wr * 64 + m * 16 + kg * 4;
                s4v o;
#pragma unroll
                for (int r = 0; r < 4; r++) o[r] = f2bf(acc[m][n][r]);
                *(s4v*)(C + (size_t)col * EMB + row0) = o;
            }
    } else {
        float bcol[4];
#pragma unroll
        for (int n = 0; n < 4; n++)
            bcol[n] = bias[nbase + wc * 64 + n * 16 + lr];
#pragma unroll
        for (int m = 0; m < 4; m++)
#pragma unroll
            for (int n = 0; n < 4; n++) {
                int col = nbase + wc * 64 + n * 16 + lr;
#pragma unroll
                for (int r = 0; r < 4; r++) {
                    int row = mbase + wr * 64 + m * 16 + kg * 4 + r;
                    float v = acc[m][n][r] + bcol[n];
                    if constexpr (EPI == 1) v = fmaxf(v, 0.f);
                    C[(size_t)row * EMB + col] = f2bf(v);
                }
            }
    }
}

// LN1: Xbf = LayerNorm(q + VO2), 32 rows/block
DEVINL void ln1_body(int bid, int tid, const float* q, const short* VO2,
                     const float* gam, const float* bet, short* Xbf) {
    int w = tid >> 6, lane = tid & 63;
    int row0 = bid * 32 + w * 8;
    for (int it = 0; it < 8; it++) {
        size_t grow = row0 + it;
        const float* qp = q + grow * EMB + lane * 8;
        float4 qa = *(const float4*)qp;
        float4 qb = *(const float4*)(qp + 4);
        s8v ao = *(const s8v*)(VO2 + grow * EMB + lane * 8);
        float v[8];
        v[0] = qa.x + bf2f(ao[0]); v[1] = qa.y + bf2f(ao[1]);
        v[2] = qa.z + bf2f(ao[2]); v[3] = qa.w + bf2f(ao[3]);
        v[4] = qb.x + bf2f(ao[4]); v[5] = qb.y + bf2f(ao[5]);
        v[6] = qb.z + bf2f(ao[6]); v[7] = qb.w + bf2f(ao[7]);
        float s = 0.f, t = 0.f;
#pragma unroll
        for (int j = 0; j < 8; j++) { s += v[j]; t += v[j] * v[j]; }
#pragma unroll
        for (int m = 32; m >= 1; m >>= 1) {
            s += __shfl_xor(s, m);
            t += __shfl_xor(t, m);
        }
        float mean = s * (1.f / EMB);
        float var = t * (1.f / EMB) - mean * mean;
        float rstd = rsqrtf(var + 1e-5f);
        s8v xb;
#pragma unroll
        for (int j = 0; j < 8; j++) {
            int col = lane * 8 + j;
            xb[j] = f2bf((v[j] - mean) * rstd * gam[col] + bet[col]);
        }
        *(s8v*)(Xbf + grow * EMB + lane * 8) = xb;
    }
}

// LN2: out = LayerNorm(Xbf + Y) f32, 32 rows/block
DEVINL void ln2_body(int bid, int tid, const short* Xbf, const short* Y,
                     const float* gam, const float* bet, float* out) {
    int w = tid >> 6, lane = tid & 63;
    int row0 = bid * 32 + w * 8;
    for (int it = 0; it < 8; it++) {
        size_t grow = row0 + it;
        s8v xv = *(const s8v*)(Xbf + grow * EMB + lane * 8);
        s8v yv = *(const s8v*)(Y + grow * EMB + lane * 8);
        float v[8];
#pragma unroll
        for (int j = 0; j < 8; j++) v[j] = bf2f(xv[j]) + bf2f(yv[j]);
        float s = 0.f, t = 0.f;
#pragma unroll
        for (int j = 0; j < 8; j++) { s += v[j]; t += v[j] * v[j]; }
#pragma unroll
        for (int m = 32; m >= 1; m >>= 1) {
            s += __shfl_xor(s, m);
            t += __shfl_xor(t, m);
        }
        float mean = s * (1.f / EMB);
        float var = t * (1.f / EMB) - mean * mean;
        float rstd = rsqrtf(var + 1e-5f);
        float xo[8];
#pragma unroll
        for (int j = 0; j < 8; j++) {
            int col = lane * 8 + j;
            xo[j] = (v[j] - mean) * rstd * gam[col] + bet[col];
        }
        float* op = out + grow * EMB + lane * 8;
        *(float4*)op = make_float4(xo[0], xo[1], xo[2], xo[3]);
        *(float4*)(op + 4) = make_float4(xo[4], xo[5], xo[6], xo[7]);
    }
}

// ---------------- the mega kernel: all phases, grid barriers between ----------
__global__ __launch_bounds__(256, 2) void mega(
    const float* __restrict__ q, const float* __restrict__ K,
    const float* __restrict__ v_W, const float* __restrict__ v_b,
    const float* __restrict__ out_W, const float* __restrict__ out_b,
    const float* __restrict__ ln1_g, const float* __restrict__ ln1_b,
    const float* __restrict__ w1, const float* __restrict__ b1,
    const float* __restrict__ w2, const float* __restrict__ b2,
    const float* __restrict__ ln2_g, const float* __restrict__ ln2_b,
    short* VWb, short* WoT, short* W1T, short* W2T, short* WcT,
    float* bc, float* part, short* SK, short* VO2, short* Xbf, short* H1,
    short* Y, float* out, unsigned* cnt, unsigned* gen) {
    __shared__ __attribute__((aligned(16))) char Ub[65536];  // 64KB union
    const int bid = blockIdx.x;
    const int tid = threadIdx.x;

    // P0: prep (592 items over 512 blocks)
    for (int item = bid; item < 592; item += NBLK) {
        prep_item(item, tid, Ub, v_W, out_W, w1, w2, K, v_b, out_b,
                  VWb, WoT, W1T, W2T, part, bc);
        __syncthreads();
    }
    gridbar(cnt, gen);

    // P1: Wc GEMM (16 tiles) + scan phase 2 (256 items)
    if (bid < 16)
        gemm_tile<2>(Ub, (bid & 7) * 2 + (bid >> 3), tid, VWb, WoT, nullptr,
                     WcT);
    else if (bid < 272)
        scan2_item(bid - 16, tid, Ub, K, part, SK);
    gridbar(cnt, gen);

    // P2: VO2 = SK @ Wc + bc
    gemm_tile<0>(Ub, (bid & 7) * 64 + (bid >> 3), tid, SK, WcT, bc, VO2);
    gridbar(cnt, gen);

    // P3: Xbf = LN1(q + VO2)
    ln1_body(bid, tid, q, VO2, ln1_g, ln1_b, Xbf);
    gridbar(cnt, gen);

    // P4: H1 = relu(Xbf @ w1 + b1)
    gemm_tile<1>(Ub, (bid & 7) * 64 + (bid >> 3), tid, Xbf, W1T, b1, H1);
    gridbar(cnt, gen);

    // P5: Y = H1 @ w2 + b2
    gemm_tile<0>(Ub, (bid & 7) * 64 + (bid >> 3), tid, H1, W2T, b2, Y);
    gridbar(cnt, gen);

    // P6: out = LN2(Xbf + Y)
    ln2_body(bid, tid, Xbf, Y, ln2_g, ln2_b, out);
}

// ---------------- launch ----------------

extern "C" void kernel_launch(void* const* d_in, const int* in_sizes, int n_in,
                              void* d_out, int out_size, void* d_ws, size_t ws_size,
                              hipStream_t stream) {
    (void)in_sizes; (void)n_in; (void)out_size; (void)ws_size;
    const float* q     = (const float*)d_in[0];
    const float* k     = (const float*)d_in[1];
    const float* v_W   = (const float*)d_in[3];
    const float* v_b   = (const float*)d_in[4];
    const float* out_W = (const float*)d_in[5];
    const float* out_b = (const float*)d_in[6];
    const float* ln1_g = (const float*)d_in[7];
    const float* ln1_b = (const float*)d_in[8];
    const float* w1    = (const float*)d_in[9];
    const float* b1    = (const float*)d_in[10];
    const float* w2    = (const float*)d_in[11];
    const float* b2    = (const float*)d_in[12];
    const float* ln2_g = (const float*)d_in[13];
    const float* ln2_b = (const float*)d_in[14];

    char* ws = (char*)d_ws;
    const size_t MB = 1u << 20;
    short* SK   = (short*)(ws);            // 16MB bf16 suffix-mean of k
    short* VO2  = (short*)(ws + 16 * MB);  // 16MB bf16 attn_out
    short* Xbf  = (short*)(ws + 32 * MB);  // 16MB bf16 x (post-LN1)
    short* H1   = (short*)(ws + 48 * MB);  // 16MB bf16 relu(x@w1+b1)
    short* Y    = (short*)(ws + 64 * MB);  // 16MB bf16 h1@w2+b2
    short* VWb  = (short*)(ws + 80 * MB);  // v_W bf16 row-major
    short* WoT  = VWb + 512 * 512;         // out_W^T bf16
    short* W1T  = WoT + 512 * 512;
    short* W2T  = W1T + 512 * 512;
    short* WcT  = W2T + 512 * 512;         // (v_W@out_W)^T bf16
    float* bc   = (float*)(WcT + 512 * 512);   // combined bias (512 f32)
    float* part = bc + EMB;                // 8*32*512 f32 chunk partials
    unsigned* bar = (unsigned*)(ws + 88 * MB);  // barrier state (cnt, gen)

    hipMemsetAsync(bar, 0, 256, stream);
    mega<<<NBLK, 256, 0, stream>>>(q, k, v_W, v_b, out_W, out_b, ln1_g, ln1_b,
                                   w1, b1, w2, b2, ln2_g, ln2_b,
                                   VWb, WoT, W1T, W2T, WcT, bc, part,
                                   SK, VO2, Xbf, H1, Y, (float*)d_out, bar,
                                   bar + 64);
}

// Round 11
// 219.719 us; speedup vs baseline: 1.7271x; 1.7271x over previous
//
#include <hip/hip_runtime.h>

typedef __attribute__((ext_vector_type(8))) short s8v;
typedef __attribute__((ext_vector_type(4))) short s4v;
typedef __attribute__((ext_vector_type(4))) float f4v;

constexpr int SEQ = 2048;
constexpr int EMB = 512;
constexpr int BATCH = 8;
constexpr int BS = BATCH * SEQ;  // 16384
constexpr int NCH = 32;          // scan chunks per batch (64 rows each)
constexpr int NBLK = 512;        // mega-kernel grid (2 blocks/CU x 256 CUs)

#define DEVINL __device__ __forceinline__

DEVINL float bf2f(short s) {
    union { unsigned u; float f; } v;
    v.u = ((unsigned)(unsigned short)s) << 16;
    return v.f;
}
DEVINL short f2bf(float f) {
    union { float f; unsigned u; } v; v.f = f;
    unsigned u = v.u;
    return (short)((u + 0x7FFFu + ((u >> 16) & 1u)) >> 16);
}
DEVINL f4v mfma16(s8v a, s8v b, f4v c) {
    return __builtin_amdgcn_mfma_f32_16x16x32_bf16(a, b, c, 0, 0, 0);
}
DEVINL s8v pack8(float4 a, float4 b) {
    s8v o;
    o[0] = f2bf(a.x); o[1] = f2bf(a.y); o[2] = f2bf(a.z); o[3] = f2bf(a.w);
    o[4] = f2bf(b.x); o[5] = f2bf(b.y); o[6] = f2bf(b.z); o[7] = f2bf(b.w);
    return o;
}
DEVINL void gload16(const short* g, short* l) {
    __builtin_amdgcn_global_load_lds(
        (const __attribute__((address_space(1))) void*)g,
        (__attribute__((address_space(3))) void*)l, 16, 0, 0);
}

// ---- software grid barrier ----
// Spin uses RELAXED agent loads (coherent-point read, NO per-iteration cache
// invalidation — R10's acquire-spin invalidated the XCD L2 every ~200ns and
// slowed worker blocks 5x). One ACQUIRE load after spin-exit publishes
// producers' writes. Release side: fetch_add ACQ_REL + release store on gen.
DEVINL void gridbar(unsigned* cnt, unsigned* gen) {
    __syncthreads();
    if (threadIdx.x == 0) {
        unsigned g = __hip_atomic_load(gen, __ATOMIC_RELAXED,
                                       __HIP_MEMORY_SCOPE_AGENT);
        unsigned a = __hip_atomic_fetch_add(cnt, 1u, __ATOMIC_ACQ_REL,
                                            __HIP_MEMORY_SCOPE_AGENT);
        if (a == (unsigned)(NBLK - 1)) {
            __hip_atomic_store(cnt, 0u, __ATOMIC_RELAXED,
                               __HIP_MEMORY_SCOPE_AGENT);
            __hip_atomic_store(gen, g + 1u, __ATOMIC_RELEASE,
                               __HIP_MEMORY_SCOPE_AGENT);
        } else {
            while (__hip_atomic_load(gen, __ATOMIC_RELAXED,
                                     __HIP_MEMORY_SCOPE_AGENT) == g)
                __builtin_amdgcn_s_sleep(8);
            (void)__hip_atomic_load(gen, __ATOMIC_ACQUIRE,
                                    __HIP_MEMORY_SCOPE_AGENT);
        }
    }
    __syncthreads();
}

// ---------------- phase bodies (verbatim from the R8 kernels) ----------------

// prep item: [0,128) v_W cast; [128,320) 64x64 transpose; [320,576) scan_p1;
// [576,592) bc matvec
DEVINL void prep_item(int item, int tid, char* Ub,
                      const float* v_W, const float* out_W, const float* w1,
                      const float* w2, const float* K, const float* v_b,
                      const float* out_b, short* VWb, short* WoT, short* W1T,
                      short* W2T, float* partial, float* bc) {
    if (item < 128) {
        int i = item * 256 + tid;
        const float* p = v_W + (size_t)i * 8;
        float4 a = *(const float4*)p;
        float4 b = *(const float4*)(p + 4);
        *(s8v*)(VWb + (size_t)i * 8) = pack8(a, b);
    } else if (item < 320) {
        short(*tile)[72] = (short(*)[72])Ub;  // 9KB
        int t = item - 128;
        int sel = t >> 6;
        const float* W = (sel == 0) ? out_W : (sel == 1 ? w1 : w2);
        short* WT = (sel == 0) ? WoT : (sel == 1 ? W1T : W2T);
        int tileid = t & 63;
        int kt = (tileid >> 3) * 64, nt = (tileid & 7) * 64;
        int r = tid >> 4;
        int c4 = (tid & 15) * 4;
#pragma unroll
        for (int p = 0; p < 4; p++) {
            int row = p * 16 + r;
            float4 v = *(const float4*)(W + (size_t)(kt + row) * EMB + nt + c4);
            tile[row][c4 + 0] = f2bf(v.x);
            tile[row][c4 + 1] = f2bf(v.y);
            tile[row][c4 + 2] = f2bf(v.z);
            tile[row][c4 + 3] = f2bf(v.w);
        }
        __syncthreads();
        int kl = (tid & 7) * 8;
        int nl = tid >> 3;
#pragma unroll
        for (int h = 0; h < 2; h++) {
            int n = h * 32 + nl;
            s8v o;
#pragma unroll
            for (int e = 0; e < 8; e++) o[e] = tile[kl + e][n];
            *(s8v*)(WT + (size_t)(nt + n) * EMB + kt + kl) = o;
        }
    } else if (item < 576) {
        float* sh = (float*)Ub;  // 8KB
        int bb = item - 320;
        int b = bb >> 5, c = bb & (NCH - 1);
        int g = tid >> 6, lane = tid & 63;
        int col8 = lane * 8;
        const float* base = K + ((size_t)b * SEQ + c * 64 + g * 16) * EMB + col8;
        float acc[8] = {};
        for (int it = 0; it < 16; it++) {
            float4 a = *(const float4*)(base + (size_t)it * EMB);
            float4 b2 = *(const float4*)(base + (size_t)it * EMB + 4);
            acc[0] += a.x; acc[1] += a.y; acc[2] += a.z; acc[3] += a.w;
            acc[4] += b2.x; acc[5] += b2.y; acc[6] += b2.z; acc[7] += b2.w;
        }
#pragma unroll
        for (int j = 0; j < 8; j++) sh[g * EMB + col8 + j] = acc[j];
        __syncthreads();
        if (g == 0) {
#pragma unroll
            for (int j = 0; j < 8; j++) {
                int e = col8 + j;
                partial[((size_t)b * NCH + c) * EMB + e] =
                    sh[e] + sh[EMB + e] + sh[2 * EMB + e] + sh[3 * EMB + e];
            }
        }
    } else {
        float* sh = (float*)Ub;  // 1KB
        int bb = item - 576;
        int nl = tid & 31, ms = tid >> 5;
        int n = bb * 32 + nl;
        float acc = 0.f;
#pragma unroll 8
        for (int mm = 0; mm < 64; mm++) {
            int m = ms * 64 + mm;
            acc = fmaf(v_b[m], out_W[(size_t)m * EMB + n], acc);
        }
        sh[tid] = acc;
        __syncthreads();
        if (tid < 32) {
            float s = 0.f;
#pragma unroll
            for (int j = 0; j < 8; j++) s += sh[j * 32 + tid];
            bc[bb * 32 + tid] = s + out_b[bb * 32 + tid];
        }
    }
}

// scan phase 2: SK[i][e] = (sum_{j>i} k[j][e]) / (SEQ-1-i)
DEVINL void scan2_item(int bid, int tid, char* Ub, const float* K,
                       const float* partial, short* SK) {
    float* wsum = (float*)Ub;  // [4][512] = 8KB
    int b = bid >> 5, c = bid & (NCH - 1);
    int g = tid >> 6, lane = tid & 63;
    int col8 = lane * 8;

    float off[8] = {}, alltot[8] = {};
    for (int cc = 0; cc < NCH; cc++) {
        const float* pp = partial + ((size_t)b * NCH + cc) * EMB + col8;
        float4 pa = *(const float4*)pp;
        float4 pb = *(const float4*)(pp + 4);
        float v[8] = {pa.x, pa.y, pa.z, pa.w, pb.x, pb.y, pb.z, pb.w};
#pragma unroll
        for (int j = 0; j < 8; j++) {
            alltot[j] += v[j];
            if (cc > c) off[j] += v[j];
        }
    }
    const float* base = K + ((size_t)b * SEQ + c * 64 + g * 16) * EMB + col8;
    {
        float acc[8] = {};
        for (int it = 0; it < 16; it++) {
            float4 a = *(const float4*)(base + (size_t)it * EMB);
            float4 bb = *(const float4*)(base + (size_t)it * EMB + 4);
            acc[0] += a.x; acc[1] += a.y; acc[2] += a.z; acc[3] += a.w;
            acc[4] += bb.x; acc[5] += bb.y; acc[6] += bb.z; acc[7] += bb.w;
        }
#pragma unroll
        for (int j = 0; j < 8; j++) wsum[g * EMB + col8 + j] = acc[j];
    }
    __syncthreads();
    float suf[8];
#pragma unroll
    for (int j = 0; j < 8; j++) {
        float s = off[j];
        for (int gg = g + 1; gg < 4; gg++) s += wsum[gg * EMB + col8 + j];
        suf[j] = s;
    }
    short* skbase = SK + ((size_t)b * SEQ + c * 64 + g * 16) * EMB + col8;
    for (int it = 15; it >= 0; it--) {
        int gi = c * 64 + g * 16 + it;
        float4 a = *(const float4*)(base + (size_t)it * EMB);
        float4 bb = *(const float4*)(base + (size_t)it * EMB + 4);
        s8v o;
        if (gi == SEQ - 1) {
            float inv = 1.0f / (float)SEQ;
#pragma unroll
            for (int j = 0; j < 8; j++) o[j] = f2bf(alltot[j] * inv);
        } else {
            float inv = __builtin_amdgcn_rcpf((float)(SEQ - 1 - gi));
#pragma unroll
            for (int j = 0; j < 8; j++) o[j] = f2bf(suf[j] * inv);
        }
        *(s8v*)(skbase + (size_t)it * EMB) = o;
        suf[0] += a.x; suf[1] += a.y; suf[2] += a.z; suf[3] += a.w;
        suf[4] += bb.x; suf[5] += bb.y; suf[6] += bb.z; suf[7] += bb.w;
    }
}

// m97-style 128x128 GEMM tile. EPI 0: +bias->bf16; 1: +bias,relu->bf16;
// 2: no bias, store transposed (C[col][row], stride EMB)
template <int EPI>
DEVINL void gemm_tile(char* Ub, int wg, int tid, const short* A,
                      const short* B, const float* bias, short* C) {
    short* L = (short*)Ub;  // 2 x 16384 shorts = 64KB
    const int mt = wg >> 2, nt = wg & 3;
    const int mbase = mt * 128, nbase = nt * 128;
    const int w = tid >> 6, lane = tid & 63;
    const int lr = lane & 15, kg = lane >> 4;
    const int wr = w >> 1, wc = w & 1;

    const short* gA[4];
    const short* gB[4];
    short* lA[4];
    short* lB[4];
#pragma unroll
    for (int inst = 0; inst < 4; inst++) {
        int Ui = inst * 256 + w * 64 + lane;  // 16B unit index, 0..1023
        int row = Ui >> 3, cu = Ui & 7;
        int csrc = cu ^ (row & 7);
        gA[inst] = A + (size_t)(mbase + row) * EMB + csrc * 8;
        gB[inst] = B + (size_t)(nbase + row) * EMB + csrc * 8;
        lA[inst] = L + (inst * 256 + w * 64) * 8;
        lB[inst] = L + 8192 + (inst * 256 + w * 64) * 8;
    }

    int aoff[4][2], boff[4][2];
#pragma unroll
    for (int m = 0; m < 4; m++)
#pragma unroll
        for (int ks = 0; ks < 2; ks++) {
            int row = wr * 64 + m * 16 + lr;
            int cu = (ks * 4 + kg) ^ (row & 7);
            aoff[m][ks] = row * 64 + cu * 8;
        }
#pragma unroll
    for (int n = 0; n < 4; n++)
#pragma unroll
        for (int ks = 0; ks < 2; ks++) {
            int row = wc * 64 + n * 16 + lr;
            int cu = (ks * 4 + kg) ^ (row & 7);
            boff[n][ks] = 8192 + row * 64 + cu * 8;
        }

    auto stage = [&](int kt, int d) {
        int koff = kt * 64;  // shorts
        int dd = d * 16384;
#pragma unroll
        for (int inst = 0; inst < 4; inst++)
            gload16(gA[inst] + koff, lA[inst] + dd);
#pragma unroll
        for (int inst = 0; inst < 4; inst++)
            gload16(gB[inst] + koff, lB[inst] + dd);
    };

    f4v acc[4][4] = {};
    stage(0, 0);
    int cur = 0;
    for (int kt = 0; kt < 8; kt++) {
        __syncthreads();  // drains vmcnt: buf[cur] staged & visible
        if (kt < 7) stage(kt + 1, cur ^ 1);
        const short* base = L + cur * 16384;
        s8v afr[4][2], bfr[4][2];
#pragma unroll
        for (int m = 0; m < 4; m++)
#pragma unroll
            for (int ks = 0; ks < 2; ks++)
                afr[m][ks] = *(const s8v*)(base + aoff[m][ks]);
#pragma unroll
        for (int n = 0; n < 4; n++)
#pragma unroll
            for (int ks = 0; ks < 2; ks++)
                bfr[n][ks] = *(const s8v*)(base + boff[n][ks]);
#pragma unroll
        for (int ks = 0; ks < 2; ks++)
#pragma unroll
            for (int m = 0; m < 4; m++)
#pragma unroll
                for (int n = 0; n < 4; n++)
                    acc[m][n] = mfma16(afr[m][ks], bfr[n][ks], acc[m][n]);
        cur ^= 1;
    }
    __syncthreads();  // protect LDS for any following phase

    if constexpr (EPI == 2) {
#pragma unroll
        for (int m = 0; m < 4; m++)
#pragma unroll
            for (int n = 0; n < 4; n++) {
                int col = nbase + wc * 64 + n * 16 + lr;
                int row0 = mbase + wr * 64 + m * 16 + kg * 4;
                s4v o;
#pragma unroll
                for (int r = 0; r < 4; r++) o[r] = f2bf(acc[m][n][r]);
                *(s4v*)(C + (size_t)col * EMB + row0) = o;
            }
    } else {
        float bcol[4];
#pragma unroll
        for (int n = 0; n < 4; n++)
            bcol[n] = bias[nbase + wc * 64 + n * 16 + lr];
#pragma unroll
        for (int m = 0; m < 4; m++)
#pragma unroll
            for (int n = 0; n < 4; n++) {
                int col = nbase + wc * 64 + n * 16 + lr;
#pragma unroll
                for (int r = 0; r < 4; r++) {
                    int row = mbase + wr * 64 + m * 16 + kg * 4 + r;
                    float v = acc[m][n][r] + bcol[n];
                    if constexpr (EPI == 1) v = fmaxf(v, 0.f);
                    C[(size_t)row * EMB + col] = f2bf(v);
                }
            }
    }
}

// LN1: Xbf = LayerNorm(q + VO2), 32 rows/block
DEVINL void ln1_body(int bid, int tid, const float* q, const short* VO2,
                     const float* gam, const float* bet, short* Xbf) {
    int w = tid >> 6, lane = tid & 63;
    int row0 = bid * 32 + w * 8;
    for (int it = 0; it < 8; it++) {
        size_t grow = row0 + it;
        const float* qp = q + grow * EMB + lane * 8;
        float4 qa = *(const float4*)qp;
        float4 qb = *(const float4*)(qp + 4);
        s8v ao = *(const s8v*)(VO2 + grow * EMB + lane * 8);
        float v[8];
        v[0] = qa.x + bf2f(ao[0]); v[1] = qa.y + bf2f(ao[1]);
        v[2] = qa.z + bf2f(ao[2]); v[3] = qa.w + bf2f(ao[3]);
        v[4] = qb.x + bf2f(ao[4]); v[5] = qb.y + bf2f(ao[5]);
        v[6] = qb.z + bf2f(ao[6]); v[7] = qb.w + bf2f(ao[7]);
        float s = 0.f, t = 0.f;
#pragma unroll
        for (int j = 0; j < 8; j++) { s += v[j]; t += v[j] * v[j]; }
#pragma unroll
        for (int m = 32; m >= 1; m >>= 1) {
            s += __shfl_xor(s, m);
            t += __shfl_xor(t, m);
        }
        float mean = s * (1.f / EMB);
        float var = t * (1.f / EMB) - mean * mean;
        float rstd = rsqrtf(var + 1e-5f);
        s8v xb;
#pragma unroll
        for (int j = 0; j < 8; j++) {
            int col = lane * 8 + j;
            xb[j] = f2bf((v[j] - mean) * rstd * gam[col] + bet[col]);
        }
        *(s8v*)(Xbf + grow * EMB + lane * 8) = xb;
    }
}

// LN2: out = LayerNorm(Xbf + Y) f32, 32 rows/block
DEVINL void ln2_body(int bid, int tid, const short* Xbf, const short* Y,
                     const float* gam, const float* bet, float* out) {
    int w = tid >> 6, lane = tid & 63;
    int row0 = bid * 32 + w * 8;
    for (int it = 0; it < 8; it++) {
        size_t grow = row0 + it;
        s8v xv = *(const s8v*)(Xbf + grow * EMB + lane * 8);
        s8v yv = *(const s8v*)(Y + grow * EMB + lane * 8);
        float v[8];
#pragma unroll
        for (int j = 0; j < 8; j++) v[j] = bf2f(xv[j]) + bf2f(yv[j]);
        float s = 0.f, t = 0.f;
#pragma unroll
        for (int j = 0; j < 8; j++) { s += v[j]; t += v[j] * v[j]; }
#pragma unroll
        for (int m = 32; m >= 1; m >>= 1) {
            s += __shfl_xor(s, m);
            t += __shfl_xor(t, m);
        }
        float mean = s * (1.f / EMB);
        float var = t * (1.f / EMB) - mean * mean;
        float rstd = rsqrtf(var + 1e-5f);
        float xo[8];
#pragma unroll
        for (int j = 0; j < 8; j++) {
            int col = lane * 8 + j;
            xo[j] = (v[j] - mean) * rstd * gam[col] + bet[col];
        }
        float* op = out + grow * EMB + lane * 8;
        *(float4*)op = make_float4(xo[0], xo[1], xo[2], xo[3]);
        *(float4*)(op + 4) = make_float4(xo[4], xo[5], xo[6], xo[7]);
    }
}

// ---------------- the mega kernel: all phases, grid barriers between ----------
__global__ __launch_bounds__(256, 2) void mega(
    const float* __restrict__ q, const float* __restrict__ K,
    const float* __restrict__ v_W, const float* __restrict__ v_b,
    const float* __restrict__ out_W, const float* __restrict__ out_b,
    const float* __restrict__ ln1_g, const float* __restrict__ ln1_b,
    const float* __restrict__ w1, const float* __restrict__ b1,
    const float* __restrict__ w2, const float* __restrict__ b2,
    const float* __restrict__ ln2_g, const float* __restrict__ ln2_b,
    short* VWb, short* WoT, short* W1T, short* W2T, short* WcT,
    float* bc, float* part, short* SK, short* VO2, short* Xbf, short* H1,
    short* Y, float* out, unsigned* cnt, unsigned* gen) {
    __shared__ __attribute__((aligned(16))) char Ub[65536];  // 64KB union
    const int bid = blockIdx.x;
    const int tid = threadIdx.x;

    // P0: prep (592 items over 512 blocks)
    for (int item = bid; item < 592; item += NBLK) {
        prep_item(item, tid, Ub, v_W, out_W, w1, w2, K, v_b, out_b,
                  VWb, WoT, W1T, W2T, part, bc);
        __syncthreads();
    }
    gridbar(cnt, gen);

    // P1: Wc GEMM (16 tiles) + scan phase 2 (256 items)
    if (bid < 16)
        gemm_tile<2>(Ub, (bid & 7) * 2 + (bid >> 3), tid, VWb, WoT, nullptr,
                     WcT);
    else if (bid < 272)
        scan2_item(bid - 16, tid, Ub, K, part, SK);
    gridbar(cnt, gen);

    // P2: VO2 = SK @ Wc + bc
    gemm_tile<0>(Ub, (bid & 7) * 64 + (bid >> 3), tid, SK, WcT, bc, VO2);
    gridbar(cnt, gen);

    // P3: Xbf = LN1(q + VO2)
    ln1_body(bid, tid, q, VO2, ln1_g, ln1_b, Xbf);
    gridbar(cnt, gen);

    // P4: H1 = relu(Xbf @ w1 + b1)
    gemm_tile<1>(Ub, (bid & 7) * 64 + (bid >> 3), tid, Xbf, W1T, b1, H1);
    gridbar(cnt, gen);

    // P5: Y = H1 @ w2 + b2
    gemm_tile<0>(Ub, (bid & 7) * 64 + (bid >> 3), tid, H1, W2T, b2, Y);
    gridbar(cnt, gen);

    // P6: out = LN2(Xbf + Y)
    ln2_body(bid, tid, Xbf, Y, ln2_g, ln2_b, out);
}

// ---------------- launch ----------------

extern "C" void kernel_launch(void* const* d_in, const int* in_sizes, int n_in,
                              void* d_out, int out_size, void* d_ws, size_t ws_size,
                              hipStream_t stream) {
    (void)in_sizes; (void)n_in; (void)out_size; (void)ws_size;
    const float* q     = (const float*)d_in[0];
    const float* k     = (const float*)d_in[1];
    const float* v_W   = (const float*)d_in[3];
    const float* v_b   = (const float*)d_in[4];
    const float* out_W = (const float*)d_in[5];
    const float* out_b = (const float*)d_in[6];
    const float* ln1_g = (const float*)d_in[7];
    const float* ln1_b = (const float*)d_in[8];
    const float* w1    = (const float*)d_in[9];
    const float* b1    = (const float*)d_in[10];
    const float* w2    = (const float*)d_in[11];
    const float* b2    = (const float*)d_in[12];
    const float* ln2_g = (const float*)d_in[13];
    const float* ln2_b = (const float*)d_in[14];

    char* ws = (char*)d_ws;
    const size_t MB = 1u << 20;
    short* SK   = (short*)(ws);            // 16MB bf16 suffix-mean of k
    short* VO2  = (short*)(ws + 16 * MB);  // 16MB bf16 attn_out
    short* Xbf  = (short*)(ws + 32 * MB);  // 16MB bf16 x (post-LN1)
    short* H1   = (short*)(ws + 48 * MB);  // 16MB bf16 relu(x@w1+b1)
    short* Y    = (short*)(ws + 64 * MB);  // 16MB bf16 h1@w2+b2
    short* VWb  = (short*)(ws + 80 * MB);  // v_W bf16 row-major
    short* WoT  = VWb + 512 * 512;         // out_W^T bf16
    short* W1T  = WoT + 512 * 512;
    short* W2T  = W1T + 512 * 512;
    short* WcT  = W2T + 512 * 512;         // (v_W@out_W)^T bf16
    float* bc   = (float*)(WcT + 512 * 512);   // combined bias (512 f32)
    float* part = bc + EMB;                // 8*32*512 f32 chunk partials
    unsigned* bar = (unsigned*)(ws + 88 * MB);  // barrier state (cnt, gen)

    hipMemsetAsync(bar, 0, 256, stream);
    mega<<<NBLK, 256, 0, stream>>>(q, k, v_W, v_b, out_W, out_b, ln1_g, ln1_b,
                                   w1, b1, w2, b2, ln2_g, ln2_b,
                                   VWb, WoT, W1T, W2T, WcT, bc, part,
                                   SK, VO2, Xbf, H1, Y, (float*)d_out, bar,
                                   bar + 64);
}

// Round 12
// 90.402 us; speedup vs baseline: 4.1976x; 2.4305x over previous
//
#include <hip/hip_runtime.h>

typedef __attribute__((ext_vector_type(8))) short s8v;
typedef __attribute__((ext_vector_type(4))) short s4v;
typedef __attribute__((ext_vector_type(4))) float f4v;

constexpr int SEQ = 2048;
constexpr int EMB = 512;
constexpr int BATCH = 8;
constexpr int BS = BATCH * SEQ;  // 16384
constexpr int NCH = 32;          // scan chunks per batch (64 rows each)

#define DEVINL __device__ __forceinline__

DEVINL float bf2f(short s) {
    union { unsigned u; float f; } v;
    v.u = ((unsigned)(unsigned short)s) << 16;
    return v.f;
}
DEVINL short f2bf(float f) {
    union { float f; unsigned u; } v; v.f = f;
    unsigned u = v.u;
    return (short)((u + 0x7FFFu + ((u >> 16) & 1u)) >> 16);
}
DEVINL f4v mfma16(s8v a, s8v b, f4v c) {
    return __builtin_amdgcn_mfma_f32_16x16x32_bf16(a, b, c, 0, 0, 0);
}
DEVINL s8v pack8(float4 a, float4 b) {
    s8v o;
    o[0] = f2bf(a.x); o[1] = f2bf(a.y); o[2] = f2bf(a.z); o[3] = f2bf(a.w);
    o[4] = f2bf(b.x); o[5] = f2bf(b.y); o[6] = f2bf(b.z); o[7] = f2bf(b.w);
    return o;
}
DEVINL void gload16(const short* g, short* l) {
    __builtin_amdgcn_global_load_lds(
        (const __attribute__((address_space(1))) void*)g,
        (__attribute__((address_space(3))) void*)l, 16, 0, 0);
}

// ---------------- combined prep kernel (592 blocks) ----------------
// [0,128):   v_W f32 -> VWb bf16 row-major (coalesced straight cast)
// [128,320): out_W/w1/w2 -> WoT/W1T/W2T bf16 [n][k], 64x64 LDS tile transpose
// [320,576): scan_p1: partial[b][c][e] = sum of 64-row chunk c of k
// [576,592): bc[n] = sum_m v_b[m]*out_W[m][n] + out_b[n] (parallel matvec)
__global__ __launch_bounds__(256) void prep_combo(
    const float* __restrict__ v_W, const float* __restrict__ out_W,
    const float* __restrict__ w1, const float* __restrict__ w2,
    const float* __restrict__ K, const float* __restrict__ v_b,
    const float* __restrict__ out_b,
    short* __restrict__ VWb, short* __restrict__ WoT,
    short* __restrict__ W1T, short* __restrict__ W2T,
    float* __restrict__ partial, float* __restrict__ bc) {
    __shared__ __attribute__((aligned(16))) char smem[4 * EMB * 4];  // 8KB worst
    const int blk = blockIdx.x;
    const int tid = threadIdx.x;

    if (blk < 128) {
        // straight cast v_W -> VWb (row-major bf16), coalesced both sides
        int i = blk * 256 + tid;  // 32768 total, 8 floats each
        const float* p = v_W + (size_t)i * 8;
        float4 a = *(const float4*)p;
        float4 b = *(const float4*)(p + 4);
        *(s8v*)(VWb + (size_t)i * 8) = pack8(a, b);
    } else if (blk < 320) {
        // 64x64 tile transpose: W[k][n] f32 -> WT[n][k] bf16
        __shared__ short tile[64][72];  // 9KB, pad 72 vs bank conflicts
        int t = blk - 128;
        int sel = t >> 6;  // 0..2
        const float* W = (sel == 0) ? out_W : (sel == 1 ? w1 : w2);
        short* WT = (sel == 0) ? WoT : (sel == 1 ? W1T : W2T);
        int tileid = t & 63;
        int kt = (tileid >> 3) * 64, nt = (tileid & 7) * 64;
        int r = tid >> 4;          // 0..15
        int c4 = (tid & 15) * 4;   // 0..60
#pragma unroll
        for (int p = 0; p < 4; p++) {
            int row = p * 16 + r;  // k within tile
            float4 v = *(const float4*)(W + (size_t)(kt + row) * EMB + nt + c4);
            tile[row][c4 + 0] = f2bf(v.x);
            tile[row][c4 + 1] = f2bf(v.y);
            tile[row][c4 + 2] = f2bf(v.z);
            tile[row][c4 + 3] = f2bf(v.w);
        }
        __syncthreads();
        int kl = (tid & 7) * 8;    // 0..56
        int nl = tid >> 3;         // 0..31
#pragma unroll
        for (int h = 0; h < 2; h++) {
            int n = h * 32 + nl;
            s8v o;
#pragma unroll
            for (int e = 0; e < 8; e++) o[e] = tile[kl + e][n];
            *(s8v*)(WT + (size_t)(nt + n) * EMB + kt + kl) = o;
        }
    } else if (blk < 576) {
        // scan phase 1
        float* sh = (float*)smem;
        int bb = blk - 320;
        int b = bb >> 5, c = bb & (NCH - 1);
        int g = tid >> 6, lane = tid & 63;
        int col8 = lane * 8;
        const float* base = K + ((size_t)b * SEQ + c * 64 + g * 16) * EMB + col8;
        float acc[8] = {};
        for (int it = 0; it < 16; it++) {
            float4 a = *(const float4*)(base + (size_t)it * EMB);
            float4 b2 = *(const float4*)(base + (size_t)it * EMB + 4);
            acc[0] += a.x; acc[1] += a.y; acc[2] += a.z; acc[3] += a.w;
            acc[4] += b2.x; acc[5] += b2.y; acc[6] += b2.z; acc[7] += b2.w;
        }
#pragma unroll
        for (int j = 0; j < 8; j++) sh[g * EMB + col8 + j] = acc[j];
        __syncthreads();
        if (g == 0) {
#pragma unroll
            for (int j = 0; j < 8; j++) {
                int e = col8 + j;
                partial[((size_t)b * NCH + c) * EMB + e] =
                    sh[e] + sh[EMB + e] + sh[2 * EMB + e] + sh[3 * EMB + e];
            }
        }
    } else {
        // bc matvec: 16 blocks x (32 cols x 8 m-slices of 64)
        float* sh = (float*)smem;
        int bb = blk - 576;
        int nl = tid & 31, ms = tid >> 5;
        int n = bb * 32 + nl;
        float acc = 0.f;
#pragma unroll 8
        for (int mm = 0; mm < 64; mm++) {
            int m = ms * 64 + mm;
            acc = fmaf(v_b[m], out_W[(size_t)m * EMB + n], acc);
        }
        sh[tid] = acc;
        __syncthreads();
        if (tid < 32) {
            float s = 0.f;
#pragma unroll
            for (int j = 0; j < 8; j++) s += sh[j * 32 + tid];
            bc[bb * 32 + tid] = s + out_b[bb * 32 + tid];
        }
    }
}

// ---------------- mid combo: Wc GEMM (16 blocks) + scan_p2 (256 blocks) ----
__global__ __launch_bounds__(256, 2) void mid_combo(
    const short* __restrict__ VWb, const short* __restrict__ WoT,
    short* __restrict__ WcT,
    const float* __restrict__ K, const float* __restrict__ partial,
    short* __restrict__ SK) {
    __shared__ __attribute__((aligned(16))) short lds[2][16384];  // 64KB
    __shared__ float wsum[4][EMB];                                 // 8KB

    if (blockIdx.x < 16) {
        const int bid = blockIdx.x;
        const int wg = (bid & 7) * 2 + (bid >> 3);
        const int mt = wg >> 2, nt = wg & 3;
        const int mbase = mt * 128, nbase = nt * 128;
        const int tid = threadIdx.x;
        const int w = tid >> 6, lane = tid & 63;
        const int lr = lane & 15, kg = lane >> 4;
        const int wr = w >> 1, wc = w & 1;

        const short* gA[4];
        const short* gB[4];
        short* lA[4];
        short* lB[4];
#pragma unroll
        for (int inst = 0; inst < 4; inst++) {
            int U = inst * 256 + w * 64 + lane;
            int row = U >> 3, cu = U & 7;
            int csrc = cu ^ (row & 7);
            gA[inst] = VWb + (size_t)(mbase + row) * EMB + csrc * 8;
            gB[inst] = WoT + (size_t)(nbase + row) * EMB + csrc * 8;
            lA[inst] = &lds[0][(inst * 256 + w * 64) * 8];
            lB[inst] = &lds[0][8192 + (inst * 256 + w * 64) * 8];
        }
        int aoff[4][2], boff[4][2];
#pragma unroll
        for (int m = 0; m < 4; m++)
#pragma unroll
            for (int ks = 0; ks < 2; ks++) {
                int row = wr * 64 + m * 16 + lr;
                int cu = (ks * 4 + kg) ^ (row & 7);
                aoff[m][ks] = row * 64 + cu * 8;
            }
#pragma unroll
        for (int n = 0; n < 4; n++)
#pragma unroll
            for (int ks = 0; ks < 2; ks++) {
                int row = wc * 64 + n * 16 + lr;
                int cu = (ks * 4 + kg) ^ (row & 7);
                boff[n][ks] = 8192 + row * 64 + cu * 8;
            }
        auto stage = [&](int kt, int d) {
            int koff = kt * 64;
            int dd = d * 16384;
#pragma unroll
            for (int inst = 0; inst < 4; inst++)
                gload16(gA[inst] + koff, lA[inst] + dd);
#pragma unroll
            for (int inst = 0; inst < 4; inst++)
                gload16(gB[inst] + koff, lB[inst] + dd);
        };
        f4v acc[4][4] = {};
        stage(0, 0);
        int cur = 0;
        for (int kt = 0; kt < 8; kt++) {
            __syncthreads();
            if (kt < 7) stage(kt + 1, cur ^ 1);
            const short* base = &lds[cur][0];
            s8v afr[4][2], bfr[4][2];
#pragma unroll
            for (int m = 0; m < 4; m++)
#pragma unroll
                for (int ks = 0; ks < 2; ks++)
                    afr[m][ks] = *(const s8v*)(base + aoff[m][ks]);
#pragma unroll
            for (int n = 0; n < 4; n++)
#pragma unroll
                for (int ks = 0; ks < 2; ks++)
                    bfr[n][ks] = *(const s8v*)(base + boff[n][ks]);
#pragma unroll
            for (int ks = 0; ks < 2; ks++)
#pragma unroll
                for (int m = 0; m < 4; m++)
#pragma unroll
                    for (int n = 0; n < 4; n++)
                        acc[m][n] = mfma16(afr[m][ks], bfr[n][ks], acc[m][n]);
            cur ^= 1;
        }
#pragma unroll
        for (int m = 0; m < 4; m++)
#pragma unroll
            for (int n = 0; n < 4; n++) {
                int col = nbase + wc * 64 + n * 16 + lr;
                int row0 = mbase + wr * 64 + m * 16 + kg * 4;
                s4v o;
#pragma unroll
                for (int r = 0; r < 4; r++) o[r] = f2bf(acc[m][n][r]);
                *(s4v*)(WcT + (size_t)col * EMB + row0) = o;
            }
    } else {
        int bid = blockIdx.x - 16;
        int b = bid >> 5, c = bid & (NCH - 1);
        int g = threadIdx.x >> 6, lane = threadIdx.x & 63;
        int col8 = lane * 8;

        float off[8] = {}, alltot[8] = {};
        for (int cc = 0; cc < NCH; cc++) {
            const float* pp = partial + ((size_t)b * NCH + cc) * EMB + col8;
            float4 pa = *(const float4*)pp;
            float4 pb = *(const float4*)(pp + 4);
            float v[8] = {pa.x, pa.y, pa.z, pa.w, pb.x, pb.y, pb.z, pb.w};
#pragma unroll
            for (int j = 0; j < 8; j++) {
                alltot[j] += v[j];
                if (cc > c) off[j] += v[j];
            }
        }
        const float* base = K + ((size_t)b * SEQ + c * 64 + g * 16) * EMB + col8;
        {
            float acc[8] = {};
            for (int it = 0; it < 16; it++) {
                float4 a = *(const float4*)(base + (size_t)it * EMB);
                float4 bb = *(const float4*)(base + (size_t)it * EMB + 4);
                acc[0] += a.x; acc[1] += a.y; acc[2] += a.z; acc[3] += a.w;
                acc[4] += bb.x; acc[5] += bb.y; acc[6] += bb.z; acc[7] += bb.w;
            }
#pragma unroll
            for (int j = 0; j < 8; j++) wsum[g][col8 + j] = acc[j];
        }
        __syncthreads();
        float suf[8];
#pragma unroll
        for (int j = 0; j < 8; j++) {
            float s = off[j];
            for (int gg = g + 1; gg < 4; gg++) s += wsum[gg][col8 + j];
            suf[j] = s;
        }
        short* skbase = SK + ((size_t)b * SEQ + c * 64 + g * 16) * EMB + col8;
        for (int it = 15; it >= 0; it--) {
            int gi = c * 64 + g * 16 + it;
            float4 a = *(const float4*)(base + (size_t)it * EMB);
            float4 bb = *(const float4*)(base + (size_t)it * EMB + 4);
            s8v o;
            if (gi == SEQ - 1) {
                float inv = 1.0f / (float)SEQ;
#pragma unroll
                for (int j = 0; j < 8; j++) o[j] = f2bf(alltot[j] * inv);
            } else {
                float inv = __builtin_amdgcn_rcpf((float)(SEQ - 1 - gi));
#pragma unroll
                for (int j = 0; j < 8; j++) o[j] = f2bf(suf[j] * inv);
            }
            *(s8v*)(skbase + (size_t)it * EMB) = o;
            suf[0] += a.x; suf[1] += a.y; suf[2] += a.z; suf[3] += a.w;
            suf[4] += bb.x; suf[5] += bb.y; suf[6] += bb.z; suf[7] += bb.w;
        }
    }
}

// ---------------- m97-style 128x128 tiled GEMM, K=512 ----------------
// EPI 0: +bias -> bf16 row-major ; EPI 1: +bias, relu -> bf16 row-major
template <int EPI>
__global__ __launch_bounds__(256, 2) void mgemm(
    const short* __restrict__ A, const short* __restrict__ B,
    const float* __restrict__ bias, short* __restrict__ C) {
    __shared__ __attribute__((aligned(16))) short lds[2][16384];  // 64KB

    const int nwg = gridDim.x;
    const int q = nwg >> 3;
    const int bid = blockIdx.x;
    const int wg = (bid & 7) * q + (bid >> 3);  // bijective (nwg % 8 == 0)
    const int mt = wg >> 2, nt = wg & 3;
    const int mbase = mt * 128, nbase = nt * 128;

    const int tid = threadIdx.x;
    const int w = tid >> 6, lane = tid & 63;
    const int lr = lane & 15, kg = lane >> 4;
    const int wr = w >> 1, wc = w & 1;

    const short* gA[4];
    const short* gB[4];
    short* lA[4];
    short* lB[4];
#pragma unroll
    for (int inst = 0; inst < 4; inst++) {
        int U = inst * 256 + w * 64 + lane;  // 16B unit index, 0..1023
        int row = U >> 3, cu = U & 7;
        int csrc = cu ^ (row & 7);
        gA[inst] = A + (size_t)(mbase + row) * EMB + csrc * 8;
        gB[inst] = B + (size_t)(nbase + row) * EMB + csrc * 8;
        lA[inst] = &lds[0][(inst * 256 + w * 64) * 8];
        lB[inst] = &lds[0][8192 + (inst * 256 + w * 64) * 8];
    }

    int aoff[4][2], boff[4][2];
#pragma unroll
    for (int m = 0; m < 4; m++)
#pragma unroll
        for (int ks = 0; ks < 2; ks++) {
            int row = wr * 64 + m * 16 + lr;
            int cu = (ks * 4 + kg) ^ (row & 7);
            aoff[m][ks] = row * 64 + cu * 8;
        }
#pragma unroll
    for (int n = 0; n < 4; n++)
#pragma unroll
        for (int ks = 0; ks < 2; ks++) {
            int row = wc * 64 + n * 16 + lr;
            int cu = (ks * 4 + kg) ^ (row & 7);
            boff[n][ks] = 8192 + row * 64 + cu * 8;
        }

    auto stage = [&](int kt, int d) {
        int koff = kt * 64;  // shorts
        int dd = d * 16384;
#pragma unroll
        for (int inst = 0; inst < 4; inst++)
            gload16(gA[inst] + koff, lA[inst] + dd);
#pragma unroll
        for (int inst = 0; inst < 4; inst++)
            gload16(gB[inst] + koff, lB[inst] + dd);
    };

    f4v acc[4][4] = {};
    stage(0, 0);
    int cur = 0;
    for (int kt = 0; kt < 8; kt++) {
        __syncthreads();  // drains vmcnt: buf[cur] staged & visible
        if (kt < 7) stage(kt + 1, cur ^ 1);
        const short* base = &lds[cur][0];
        s8v afr[4][2], bfr[4][2];
#pragma unroll
        for (int m = 0; m < 4; m++)
#pragma unroll
            for (int ks = 0; ks < 2; ks++)
                afr[m][ks] = *(const s8v*)(base + aoff[m][ks]);
#pragma unroll
        for (int n = 0; n < 4; n++)
#pragma unroll
            for (int ks = 0; ks < 2; ks++)
                bfr[n][ks] = *(const s8v*)(base + boff[n][ks]);
#pragma unroll
        for (int ks = 0; ks < 2; ks++)
#pragma unroll
            for (int m = 0; m < 4; m++)
#pragma unroll
                for (int n = 0; n < 4; n++)
                    acc[m][n] = mfma16(afr[m][ks], bfr[n][ks], acc[m][n]);
        cur ^= 1;
    }

    float bcol[4];
#pragma unroll
    for (int n = 0; n < 4; n++) bcol[n] = bias[nbase + wc * 64 + n * 16 + lr];
#pragma unroll
    for (int m = 0; m < 4; m++)
#pragma unroll
        for (int n = 0; n < 4; n++) {
            int col = nbase + wc * 64 + n * 16 + lr;
#pragma unroll
            for (int r = 0; r < 4; r++) {
                int row = mbase + wr * 64 + m * 16 + kg * 4 + r;
                float v = acc[m][n][r] + bcol[n];
                if constexpr (EPI == 1) v = fmaxf(v, 0.f);
                C[(size_t)row * EMB + col] = f2bf(v);
            }
        }
}

// ---------------- LN1: Xbf = LayerNorm(q + VO2) (bf16 out), 16 rows/block ----
__global__ __launch_bounds__(256) void ln1_kernel(
    const float* __restrict__ q, const short* __restrict__ VO2,
    const float* __restrict__ gam, const float* __restrict__ bet,
    short* __restrict__ Xbf) {
    int w = threadIdx.x >> 6, lane = threadIdx.x & 63;
    int row0 = blockIdx.x * 16 + w * 4;
    for (int it = 0; it < 4; it++) {
        size_t grow = row0 + it;
        const float* qp = q + grow * EMB + lane * 8;
        float4 qa = *(const float4*)qp;
        float4 qb = *(const float4*)(qp + 4);
        s8v ao = *(const s8v*)(VO2 + grow * EMB + lane * 8);
        float v[8];
        v[0] = qa.x + bf2f(ao[0]); v[1] = qa.y + bf2f(ao[1]);
        v[2] = qa.z + bf2f(ao[2]); v[3] = qa.w + bf2f(ao[3]);
        v[4] = qb.x + bf2f(ao[4]); v[5] = qb.y + bf2f(ao[5]);
        v[6] = qb.z + bf2f(ao[6]); v[7] = qb.w + bf2f(ao[7]);
        float s = 0.f, t = 0.f;
#pragma unroll
        for (int j = 0; j < 8; j++) { s += v[j]; t += v[j] * v[j]; }
#pragma unroll
        for (int m = 32; m >= 1; m >>= 1) {
            s += __shfl_xor(s, m);
            t += __shfl_xor(t, m);
        }
        float mean = s * (1.f / EMB);
        float var = t * (1.f / EMB) - mean * mean;
        float rstd = rsqrtf(var + 1e-5f);
        s8v xb;
#pragma unroll
        for (int j = 0; j < 8; j++) {
            int col = lane * 8 + j;
            xb[j] = f2bf((v[j] - mean) * rstd * gam[col] + bet[col]);
        }
        *(s8v*)(Xbf + grow * EMB + lane * 8) = xb;
    }
}

// ---------------- LN2: out = LayerNorm(Xbf + Y) (f32 out), 16 rows/block ----
__global__ __launch_bounds__(256) void ln2_kernel(
    const short* __restrict__ Xbf, const short* __restrict__ Y,
    const float* __restrict__ gam, const float* __restrict__ bet,
    float* __restrict__ out) {
    int w = threadIdx.x >> 6, lane = threadIdx.x & 63;
    int row0 = blockIdx.x * 16 + w * 4;
    for (int it = 0; it < 4; it++) {
        size_t grow = row0 + it;
        s8v xv = *(const s8v*)(Xbf + grow * EMB + lane * 8);
        s8v yv = *(const s8v*)(Y + grow * EMB + lane * 8);
        float v[8];
#pragma unroll
        for (int j = 0; j < 8; j++) v[j] = bf2f(xv[j]) + bf2f(yv[j]);
        float s = 0.f, t = 0.f;
#pragma unroll
        for (int j = 0; j < 8; j++) { s += v[j]; t += v[j] * v[j]; }
#pragma unroll
        for (int m = 32; m >= 1; m >>= 1) {
            s += __shfl_xor(s, m);
            t += __shfl_xor(t, m);
        }
        float mean = s * (1.f / EMB);
        float var = t * (1.f / EMB) - mean * mean;
        float rstd = rsqrtf(var + 1e-5f);
        float xo[8];
#pragma unroll
        for (int j = 0; j < 8; j++) {
            int col = lane * 8 + j;
            xo[j] = (v[j] - mean) * rstd * gam[col] + bet[col];
        }
        float* op = out + grow * EMB + lane * 8;
        *(float4*)op = make_float4(xo[0], xo[1], xo[2], xo[3]);
        *(float4*)(op + 4) = make_float4(xo[4], xo[5], xo[6], xo[7]);
    }
}

// ---------------- launch ----------------

extern "C" void kernel_launch(void* const* d_in, const int* in_sizes, int n_in,
                              void* d_out, int out_size, void* d_ws, size_t ws_size,
                              hipStream_t stream) {
    (void)in_sizes; (void)n_in; (void)out_size; (void)ws_size;
    const float* q     = (const float*)d_in[0];
    const float* k     = (const float*)d_in[1];
    const float* v_W   = (const float*)d_in[3];
    const float* v_b   = (const float*)d_in[4];
    const float* out_W = (const float*)d_in[5];
    const float* out_b = (const float*)d_in[6];
    const float* ln1_g = (const float*)d_in[7];
    const float* ln1_b = (const float*)d_in[8];
    const float* w1    = (const float*)d_in[9];
    const float* b1    = (const float*)d_in[10];
    const float* w2    = (const float*)d_in[11];
    const float* b2    = (const float*)d_in[12];
    const float* ln2_g = (const float*)d_in[13];
    const float* ln2_b = (const float*)d_in[14];

    char* ws = (char*)d_ws;
    const size_t MB = 1u << 20;
    short* SK   = (short*)(ws);            // 16MB bf16 suffix-mean of k
    short* VO2  = (short*)(ws + 16 * MB);  // 16MB bf16 attn_out = SK@Wc + bc
    short* Xbf  = (short*)(ws + 32 * MB);  // 16MB bf16 x (post-LN1)
    short* H1   = (short*)(ws + 48 * MB);  // 16MB bf16 relu(x@w1+b1)
    short* Y    = (short*)(ws + 64 * MB);  // 16MB bf16 h1@w2+b2
    short* VWb  = (short*)(ws + 80 * MB);  // v_W bf16 row-major
    short* WoT  = VWb + 512 * 512;         // out_W^T bf16
    short* W1T  = WoT + 512 * 512;
    short* W2T  = W1T + 512 * 512;
    short* WcT  = W2T + 512 * 512;         // (v_W@out_W)^T bf16
    float* bc   = (float*)(WcT + 512 * 512);   // combined bias (512 f32)
    float* part = bc + EMB;                // 8*32*512 f32 chunk partials

    // weight casts/transposes + scan phase 1 + combined bias, one launch
    prep_combo<<<592, 256, 0, stream>>>(v_W, out_W, w1, w2, k, v_b, out_b,
                                        VWb, WoT, W1T, W2T, part, bc);
    // Wc GEMM (16 blocks) + suffix-mean scan (256 blocks), one launch
    mid_combo<<<272, 256, 0, stream>>>(VWb, WoT, WcT, k, part, SK);
    // attn_out = SK @ Wc + bc
    mgemm<0><<<(BS / 128) * 4, 256, 0, stream>>>(SK, WcT, bc, VO2);
    // x = LN1(q + attn_out)
    ln1_kernel<<<BS / 16, 256, 0, stream>>>(q, VO2, ln1_g, ln1_b, Xbf);
    // h1 = relu(x @ w1 + b1)
    mgemm<1><<<(BS / 128) * 4, 256, 0, stream>>>(Xbf, W1T, b1, H1);
    // y = h1 @ w2 + b2
    mgemm<0><<<(BS / 128) * 4, 256, 0, stream>>>(H1, W2T, b2, Y);
    // out = LN2(x + y)
    ln2_kernel<<<BS / 16, 256, 0, stream>>>(Xbf, Y, ln2_g, ln2_b, (float*)d_out);
}